// Round 18
// baseline (148.242 us; speedup 1.0000x reference)
//
#include <hip/hip_runtime.h>
#include <hip/hip_bf16.h>
#include <math.h>

#define B_SZ 16
#define C_IN 256
#define HEADS 4
#define DHEAD 32
#define INNER 128
#define QKV_CH 384
#define N_PIX 4096
#define SCALE_Q 0.17677669529663687f  // 32^-0.5
#define GN_EPS 1e-5f
#define NCHK 32  // ctx chunks of K=128

typedef __attribute__((ext_vector_type(8))) short s16x8;
typedef __attribute__((ext_vector_type(4))) float f32x4;
typedef __attribute__((ext_vector_type(8))) unsigned short u16x8;
typedef __attribute__((ext_vector_type(4))) unsigned short u16x4;

#define VMCNT(n) asm volatile("s_waitcnt vmcnt(" #n ")" ::: "memory")
#define LGKMCNT0 asm volatile("s_waitcnt lgkmcnt(0)" ::: "memory")

__device__ __forceinline__ float waveSum(float v) {
#pragma unroll
  for (int off = 32; off > 0; off >>= 1) v += __shfl_down(v, off, 64);
  return v;
}
__device__ __forceinline__ unsigned short f2bf(float f) {  // RNE
  unsigned int u = __builtin_bit_cast(unsigned int, f);
  unsigned int r = 0x7FFFu + ((u >> 16) & 1u);
  return (unsigned short)((u + r) >> 16);
}
__device__ __forceinline__ float bf2f(unsigned short u) {
  unsigned int x = ((unsigned int)u) << 16;
  return __builtin_bit_cast(float, x);
}

// ---------------------------------------------------------------------------
// K0: convert weights to bf16 (tiny) + re-zero the grid-barrier counter
// (stream-ordered before out_full; re-runs each launch iteration).
// ---------------------------------------------------------------------------
__global__ __launch_bounds__(256) void cvt_w(const float* __restrict__ wq,
                                             const float* __restrict__ wo,
                                             unsigned short* __restrict__ wqb,
                                             unsigned short* __restrict__ wob,
                                             unsigned int* __restrict__ bar) {
  const int i = blockIdx.x * 256 + threadIdx.x;
  if (i == 0) *bar = 0u;
  if (i < QKV_CH * C_IN) wqb[i] = f2bf(wq[i]);
  if (i < C_IN * INNER) wob[i] = f2bf(wo[i]);
}

// ---------------------------------------------------------------------------
// K1: qkv GEMM — FROZEN r8 core (best of 10 structural variants, 41-52us
// band). 2D grid, no XCD swizzle (r7/r8 A/B). Fused q-softmax epilogue.
// launch_bounds(512,4): VGPR cap 128 (r6 lesson).
// ---------------------------------------------------------------------------
__global__ __launch_bounds__(512, 4) void qkv_gemm(const unsigned short* __restrict__ A,
                                                   const float* __restrict__ X,
                                                   unsigned short* __restrict__ Out,
                                                   unsigned short* __restrict__ qsm_t) {
  const int b = blockIdx.y;
  const int n0 = blockIdx.x * 64;
  const int tid = threadIdx.x;
  const int w = tid >> 6, l = tid & 63;
  const int lr = l & 15, kg = l >> 4;
  const int wm = w >> 1, wn = w & 1;  // 4M x 2N wave grid on (192, 64)

  __shared__ char lds[65536];
  char* As = lds;          // 2 x 24576 B : [half][192 m][64 c] bf16, swizzled
  char* Bs = lds + 49152;  // 2 x 8192 B  : [pb][64 n][64 c] bf16, swizzled

  const int c_loc = ((tid >> 3) & 7) + w * 8;  // 0..63 (c within chunk)
  const int oct = tid & 7;                     // n-octet
  const float* xbase = X + (size_t)b * C_IN * N_PIX + (size_t)c_loc * N_PIX + n0 + oct * 8;

  // ---- A stage: 3x global_load_lds (16B), dest linear, src pre-swizzled ----
  auto ISSUE_A = [&](int kc, int half) {
#pragma unroll
    for (int it = 0; it < 3; ++it) {
      const int idx = it * 512 + tid;
      const int r = idx >> 3;  // local m-row 0..191
      const int srcb = ((idx & 7) << 4) ^ ((r & 7) << 4);
      __builtin_amdgcn_global_load_lds(
          (const __attribute__((address_space(1))) void*)((const char*)A +
              ((size_t)(half * 192 + r) * C_IN + kc * 64) * 2 + srcb),
          (__attribute__((address_space(3))) void*)(As + half * 24576 + idx * 16), 16, 0, 0);
    }
  };

  f32x4 xr0, xr1;  // 8 fp32: x[c_loc][n0 + oct*8 .. +8)
  auto ISSUE_X = [&](int kc) {
    const float* xp = xbase + (size_t)(kc * 64) * N_PIX;
    xr0 = *reinterpret_cast<const f32x4*>(xp);
    xr1 = *reinterpret_cast<const f32x4*>(xp + 4);
  };

  auto WRITE_B = [&](int pb) {
#pragma unroll
    for (int j = 0; j < 8; ++j) {
      const int n = oct * 8 + j;
      const float v = (j < 4) ? xr0[j] : xr1[j - 4];
      *reinterpret_cast<unsigned short*>(
          Bs + pb * 8192 + n * 128 + ((2 * c_loc) ^ (((n ^ (n >> 3)) & 7) << 4))) = f2bf(v);
    }
  };

  f32x4 acc[2][3][2] = {};

  auto COMPUTE = [&](int kc, int half) {
    const char* Ab = As + half * 24576;
    const char* Bb = Bs + (kc & 1) * 8192;
#pragma unroll
    for (int ks = 0; ks < 2; ++ks) {
      const int kb = ks * 64 + kg * 16;
      s16x8 av[3], bv[2];
#pragma unroll
      for (int i = 0; i < 3; ++i) {
        const int r = wm * 48 + i * 16 + lr;
        av[i] = *reinterpret_cast<const s16x8*>(Ab + r * 128 + (kb ^ ((r & 7) << 4)));
      }
#pragma unroll
      for (int j = 0; j < 2; ++j) {
        const int n = wn * 32 + j * 16 + lr;
        bv[j] = *reinterpret_cast<const s16x8*>(Bb + n * 128 +
                                                (kb ^ (((n ^ (n >> 3)) & 7) << 4)));
      }
#pragma unroll
      for (int i = 0; i < 3; ++i)
#pragma unroll
        for (int j = 0; j < 2; ++j)
          acc[half][i][j] =
              __builtin_amdgcn_mfma_f32_16x16x32_bf16(av[i], bv[j], acc[half][i][j], 0, 0, 0);
    }
  };

  // ---- prologue ----
  ISSUE_A(0, 0);
  ISSUE_X(0);
  VMCNT(0);  // A(0,0) AND x(0) landed
  WRITE_B(0);
  LGKMCNT0;
  __builtin_amdgcn_s_barrier();  // As buf0 + Bs buf0 visible to all waves

  for (int kc = 0; kc < 4; ++kc) {
    // -- substep (kc,0): compute A-half0; prefetch A-half1 (+ next x) --
    ISSUE_A(kc, 1);
    if (kc < 3) {
      ISSUE_X(kc + 1);
      VMCNT(5);  // A(kc,0) (3 oldest) done
    } else {
      VMCNT(3);  // A(3,0) done
    }
    __builtin_amdgcn_s_barrier();  // RAW: all waves' A(kc,0) loads visible
    COMPUTE(kc, 0);
    LGKMCNT0;
    __builtin_amdgcn_s_barrier();  // WAR: buf0 free for next writer
    // -- substep (kc,1): compute A-half1; prefetch next A-half0; write next B --
    if (kc < 3) {
      ISSUE_A(kc + 1, 0);
      VMCNT(3);  // A(kc,1)+x(kc+1) done
    } else {
      VMCNT(0);
    }
    __builtin_amdgcn_s_barrier();  // RAW: all waves' A(kc,1) loads visible
    if (kc < 3) WRITE_B((kc + 1) & 1);
    COMPUTE(kc, 1);
    LGKMCNT0;
    __builtin_amdgcn_s_barrier();  // B visible; close half1 reads
  }
  // loop ends with all ds_reads drained + barrier -> LDS free for reuse

  // ---- epilogue part 1: K/V global stores (skip q channels m<128) ----
  unsigned short* Ob = Out + (size_t)b * QKV_CH * N_PIX;
#pragma unroll
  for (int half = 0; half < 2; ++half)
#pragma unroll
    for (int i = 0; i < 3; ++i) {
      const int mt = wm * 48 + i * 16;  // tile base within half
      if (half == 1 || mt >= 128) {
        const int mrow = half * 192 + mt + kg * 4;
#pragma unroll
        for (int j = 0; j < 2; ++j) {
          const int col = n0 + wn * 32 + j * 16 + lr;
#pragma unroll
          for (int r = 0; r < 4; ++r)
            Ob[(size_t)(mrow + r) * N_PIX + col] = f2bf(acc[half][i][j][r]);
        }
      }
    }

  // ---- epilogue part 2: stage q-acc (fp32) into LDS qs[64 n][132] ----
  float* qs = (float*)lds;  // 64*132*4 = 33792 B
#pragma unroll
  for (int i = 0; i < 3; ++i) {
    const int mt = wm * 48 + i * 16;
    if (mt < 128) {
      const int rowb = mt + kg * 4;
#pragma unroll
      for (int j = 0; j < 2; ++j) {
        const int c_l = wn * 32 + j * 16 + lr;
        *reinterpret_cast<f32x4*>(qs + c_l * 132 + rowb) = acc[0][i][j];
      }
    }
  }
  LGKMCNT0;
  __builtin_amdgcn_s_barrier();  // q panel visible

  // ---- epilogue part 3: softmax over d per (n, h); write qsm_t bf16 ----
  if (tid < 256) {
    const int n_loc = tid & 63, h = tid >> 6;  // wave-uniform h
    const float* qrow = qs + n_loc * 132 + h * 32;
    f32x4 qv[8];
#pragma unroll
    for (int c = 0; c < 8; ++c) qv[c] = *reinterpret_cast<const f32x4*>(qrow + c * 4);
    float m = qv[0][0];
#pragma unroll
    for (int c = 0; c < 8; ++c)
#pragma unroll
      for (int r = 0; r < 4; ++r) m = fmaxf(m, qv[c][r]);
    float e[32];
    float s = 0.f;
#pragma unroll
    for (int c = 0; c < 8; ++c)
#pragma unroll
      for (int r = 0; r < 4; ++r) {
        e[c * 4 + r] = __expf(qv[c][r] - m);
        s += e[c * 4 + r];
      }
    const float inv = SCALE_Q / s;
    unsigned short* ob = qsm_t + ((size_t)b * N_PIX + n0 + n_loc) * INNER + h * DHEAD;
#pragma unroll
    for (int d8 = 0; d8 < 4; ++d8) {
      u16x8 pk;
#pragma unroll
      for (int r = 0; r < 8; ++r) pk[r] = f2bf(e[d8 * 8 + r] * inv);
      *reinterpret_cast<u16x8*>(&ob[d8 * 8]) = pk;
    }
  }
}

// ---------------------------------------------------------------------------
// K2: ctx via MFMA, wave-per-(b,h,chunk). chunk = 128 n values.
// grid 512 (XCD-swizzled — r12 A/B: removal was worse; keep), block 256.
// ---------------------------------------------------------------------------
__global__ __launch_bounds__(256) void ctx_mfma(const unsigned short* __restrict__ qkv,
                                                float* __restrict__ ctxp,
                                                float* __restrict__ mpart,
                                                float* __restrict__ spart) {
  const int id = blockIdx.x;
  const int rank = (id & 7) * 64 + (id >> 3);  // XCD-contiguous
  const int wid = rank * 4 + (threadIdx.x >> 6);
  const int l = threadIdx.x & 63;
  const int b = wid >> 7;
  const int h = (wid >> 5) & 3;
  const int c = wid & 31;
  const int lr = l & 15, kg = l >> 4;
  const unsigned short* kb =
      qkv + ((size_t)b * QKV_CH + INNER + h * DHEAD) * N_PIX + c * 128 + kg * 8;
  const unsigned short* vb = kb + (size_t)INNER * N_PIX;

  u16x8 kf[2][4], vf[2][4];
#pragma unroll
  for (int dt = 0; dt < 2; ++dt)
#pragma unroll
    for (int ks = 0; ks < 4; ++ks) {
      kf[dt][ks] = *reinterpret_cast<const u16x8*>(kb + (size_t)(dt * 16 + lr) * N_PIX + ks * 32);
      vf[dt][ks] = *reinterpret_cast<const u16x8*>(vb + (size_t)(dt * 16 + lr) * N_PIX + ks * 32);
    }
  float kv[2][4][8];
  float m[2] = {-INFINITY, -INFINITY};
#pragma unroll
  for (int dt = 0; dt < 2; ++dt)
#pragma unroll
    for (int ks = 0; ks < 4; ++ks)
#pragma unroll
      for (int j = 0; j < 8; ++j) {
        kv[dt][ks][j] = bf2f(kf[dt][ks][j]);
        m[dt] = fmaxf(m[dt], kv[dt][ks][j]);
      }
#pragma unroll
  for (int dt = 0; dt < 2; ++dt) {
    m[dt] = fmaxf(m[dt], __shfl_xor(m[dt], 16, 64));
    m[dt] = fmaxf(m[dt], __shfl_xor(m[dt], 32, 64));
  }
  float s[2] = {0.f, 0.f};
  s16x8 ka[2][4];
#pragma unroll
  for (int dt = 0; dt < 2; ++dt)
#pragma unroll
    for (int ks = 0; ks < 4; ++ks)
#pragma unroll
      for (int j = 0; j < 8; ++j) {
        const float e = __expf(kv[dt][ks][j] - m[dt]);
        s[dt] += e;
        ka[dt][ks][j] = (short)f2bf(e);
      }
#pragma unroll
  for (int dt = 0; dt < 2; ++dt) {
    s[dt] += __shfl_xor(s[dt], 16, 64);
    s[dt] += __shfl_xor(s[dt], 32, 64);
  }
  f32x4 acc[2][2] = {};
#pragma unroll
  for (int ks = 0; ks < 4; ++ks)
#pragma unroll
    for (int dt = 0; dt < 2; ++dt)
#pragma unroll
      for (int et = 0; et < 2; ++et)
        acc[dt][et] = __builtin_amdgcn_mfma_f32_16x16x32_bf16(
            ka[dt][ks], __builtin_bit_cast(s16x8, vf[et][ks]), acc[dt][et], 0, 0, 0);

  float* cp = ctxp + (size_t)wid * 1024;
#pragma unroll
  for (int dt = 0; dt < 2; ++dt)
#pragma unroll
    for (int et = 0; et < 2; ++et)
#pragma unroll
      for (int r = 0; r < 4; ++r)
        cp[(dt * 16 + kg * 4 + r) * 32 + et * 16 + lr] = acc[dt][et][r];
  if (kg == 0) {
    mpart[wid * 32 + lr] = m[0];
    mpart[wid * 32 + 16 + lr] = m[1];
    spart[wid * 32 + lr] = s[0];
    spart[wid * 32 + 16 + lr] = s[1];
  }
}

// ---------------------------------------------------------------------------
// K3 (ctx_reduce + weff merged, latency-fixed r11): grid 64 = (b*4+h),
// block 256. Unrolled chunk loads (concurrent issue) + f32x4 LDS reads.
// ---------------------------------------------------------------------------
__global__ __launch_bounds__(256) void ctx_weff(const float* __restrict__ ctxp,
                                                const float* __restrict__ mpart,
                                                const float* __restrict__ spart,
                                                const unsigned short* __restrict__ wo,
                                                unsigned short* __restrict__ weff) {
  const int bh = blockIdx.x;
  const int b = bh >> 2, h = bh & 3;
  const int tid = threadIdx.x;
  __shared__ float ms[NCHK][32], ss[NCHK][32], fac[NCHK][32];
  __shared__ float inv_l[32];
  __shared__ float cf[1024];  // [d][e]
#pragma unroll
  for (int i = 0; i < 4; ++i) {
    const int idx = tid + i * 256;  // c*32+d
    ms[idx >> 5][idx & 31] = mpart[(size_t)bh * 1024 + idx];
    ss[idx >> 5][idx & 31] = spart[(size_t)bh * 1024 + idx];
  }
  __syncthreads();
  if (tid < 32) {
    const int d = tid;
    float M = -INFINITY;
#pragma unroll
    for (int c = 0; c < NCHK; ++c) M = fmaxf(M, ms[c][d]);
    float den = 0.f;
#pragma unroll
    for (int c = 0; c < NCHK; ++c) {
      const float f = __expf(ms[c][d] - M);
      fac[c][d] = f;
      den += f * ss[c][d];
    }
    inv_l[d] = 1.0f / den;
  }
  __syncthreads();
  const float* cp = ctxp + (size_t)bh * (NCHK * 1024);
  for (int i = 0; i < 4; ++i) {
    const int idx = tid + i * 256;  // d*32+e
    const int d = idx >> 5;
    float vals[NCHK];
#pragma unroll
    for (int c = 0; c < NCHK; ++c) vals[c] = cp[(size_t)c * 1024 + idx];
    float a = 0.f;
#pragma unroll
    for (int c = 0; c < NCHK; ++c) a += fac[c][d] * vals[c];
    cf[idx] = a * inv_l[d];
  }
  __syncthreads();

  // ---- Phase 2: w_eff for this (b,h); thread owns channel o = tid ----
  const int o = tid;
  float wr[32];
  const unsigned short* wp = wo + (size_t)o * INNER + h * DHEAD;
#pragma unroll
  for (int e8 = 0; e8 < 4; ++e8) {
    u16x8 v = *reinterpret_cast<const u16x8*>(wp + e8 * 8);
#pragma unroll
    for (int j = 0; j < 8; ++j) wr[e8 * 8 + j] = bf2f(v[j]);
  }
  unsigned short* op = weff + ((size_t)b * C_IN + o) * INNER + h * DHEAD;
#pragma unroll
  for (int d8 = 0; d8 < 4; ++d8) {
    u16x8 outv;
#pragma unroll
    for (int dd = 0; dd < 8; ++dd) {
      const float* cr = cf + (d8 * 8 + dd) * 32;
      float a = 0.f;
#pragma unroll
      for (int e4 = 0; e4 < 8; ++e4) {
        const f32x4 c4 = *reinterpret_cast<const f32x4*>(cr + e4 * 4);  // b128 bcast
#pragma unroll
        for (int j = 0; j < 4; ++j) a += wr[e4 * 4 + j] * c4[j];
      }
      outv[dd] = f2bf(a);
    }
    *reinterpret_cast<u16x8*>(op + d8 * 8) = outv;
  }
}

// ---------------------------------------------------------------------------
// K4 (FUSED out_stats+out_apply via software grid barrier): GEMM once ->
// per-block partials -> device-scope release (threadfence+atomicAdd) ->
// bounded acquire-spin until all 1024 blocks arrive -> reduce batch stats
// from registers -> normalize + write. Co-residency proof: grid 1024 =
// exactly 4 blocks/CU x 256 CU; launch_bounds(256,4) caps VGPR<=128 (16
// waves/CU per m69), LDS 16.9KB << 40KB/block. No block retires before the
// barrier, so the CP fills every slot. Bounded spin (2^24) fails fast on a
// broken assumption instead of hanging. Counter re-zeroed by cvt_w each
// launch (stream-ordered). grid 1024 (XCD-swizzled), block 256.
// ---------------------------------------------------------------------------
__global__ __launch_bounds__(256, 4) void out_full(
    const unsigned short* __restrict__ A, const unsigned short* __restrict__ Bm,
    float* __restrict__ Out, const float* __restrict__ bias,
    float* __restrict__ gn_part, const float* __restrict__ gamma,
    const float* __restrict__ beta, unsigned int* __restrict__ bar) {
  const int id = blockIdx.x;
  const int rank = (id & 7) * 128 + (id >> 3);  // XCD-contiguous
  const int b = rank >> 6;
  const int m0 = ((rank >> 5) & 1) * 128;
  const int n0 = (rank & 31) * 128;
  const int tid = threadIdx.x;
  const int w = tid >> 6, l = tid & 63;
  const int lr = l & 15, kg = l >> 4;
  const int mOff = (w >> 1) * 64, nOff = (w & 1) * 64;

  __shared__ unsigned short As[8192];
  __shared__ unsigned short Bs[8192];
  __shared__ float red[8];

  const unsigned short* Ab = A + (size_t)b * C_IN * INNER;  // per-batch w_eff
  const unsigned short* Bb = Bm + (size_t)b * N_PIX * INNER;
  f32x4 acc[4][4] = {};

  for (int kc = 0; kc < INNER; kc += 64) {
#pragma unroll
    for (int s = 0; s < 4; ++s) {
      const int blk = (w * 4 + s) * 64 + l;
      const int r = blk >> 3;
      const int c = ((blk & 7) ^ (r & 7)) << 3;
      __builtin_amdgcn_global_load_lds(
          (const __attribute__((address_space(1))) void*)(Ab + (size_t)(m0 + r) * INNER + kc + c),
          (__attribute__((address_space(3))) void*)((char*)As + (w * 4 + s) * 1024), 16, 0, 0);
      __builtin_amdgcn_global_load_lds(
          (const __attribute__((address_space(1))) void*)(Bb + (size_t)(n0 + r) * INNER + kc + c),
          (__attribute__((address_space(3))) void*)((char*)Bs + (w * 4 + s) * 1024), 16, 0, 0);
    }
    __syncthreads();
#pragma unroll
    for (int ks = 0; ks < 2; ++ks) {
      const int kbyte = ks * 64 + kg * 16;
      s16x8 av[4], bv[4];
#pragma unroll
      for (int i = 0; i < 4; ++i) {
        const int row = mOff + i * 16 + lr;
        av[i] = *reinterpret_cast<const s16x8*>(
            (const char*)As + row * 128 + (kbyte ^ ((row & 7) << 4)));
      }
#pragma unroll
      for (int j = 0; j < 4; ++j) {
        const int row = nOff + j * 16 + lr;
        bv[j] = *reinterpret_cast<const s16x8*>(
            (const char*)Bs + row * 128 + (kbyte ^ ((row & 7) << 4)));
      }
#pragma unroll
      for (int i = 0; i < 4; ++i)
#pragma unroll
        for (int j = 0; j < 4; ++j)
          acc[i][j] = __builtin_amdgcn_mfma_f32_16x16x32_bf16(av[i], bv[j], acc[i][j], 0, 0, 0);
    }
    __syncthreads();
  }

  // ---- stats partials (with bias) ----
  {
    float s = 0.f, s2 = 0.f;
#pragma unroll
    for (int i = 0; i < 4; ++i) {
      const int rowb = m0 + mOff + i * 16 + kg * 4;
#pragma unroll
      for (int r = 0; r < 4; ++r) {
        const float bvs = bias[rowb + r];
#pragma unroll
        for (int j = 0; j < 4; ++j) {
          const float v = acc[i][j][r] + bvs;
          s += v;
          s2 += v * v;
        }
      }
    }
    const float S = waveSum(s), S2 = waveSum(s2);
    if (l == 0) {
      red[w] = S;
      red[4 + w] = S2;
    }
    __syncthreads();
    if (tid == 0) {
      gn_part[(size_t)rank * 2 + 0] = red[0] + red[1] + red[2] + red[3];
      gn_part[(size_t)rank * 2 + 1] = red[4] + red[5] + red[6] + red[7];
    }
  }

  // ---- software grid barrier ----
  __syncthreads();
  if (tid == 0) {
    __threadfence();  // release: gn_part store visible device-wide
    __hip_atomic_fetch_add(bar, 1u, __ATOMIC_ACQ_REL, __HIP_MEMORY_SCOPE_AGENT);
    for (long t = 0; t < (1L << 24); ++t) {  // bounded: fail-fast, no hang
      if (__hip_atomic_load(bar, __ATOMIC_ACQUIRE, __HIP_MEMORY_SCOPE_AGENT) >= 1024u) break;
      __builtin_amdgcn_s_sleep(8);
    }
  }
  __syncthreads();  // block ordered behind lane-0's acquire (L1/L2 invalidated)

  // ---- reduce this batch's 64 partials (each wave redundantly) ----
  const int i64 = tid & 63;
  float ps = gn_part[(size_t)(b * 64 + i64) * 2 + 0];
  float ps2 = gn_part[(size_t)(b * 64 + i64) * 2 + 1];
  ps = waveSum(ps);
  ps2 = waveSum(ps2);
  const float invn = 1.0f / (float)(C_IN * N_PIX);
  const float mean = __shfl(ps, 0, 64) * invn;
  const float var = __shfl(ps2, 0, 64) * invn - mean * mean;
  const float istd = rsqrtf(var + GN_EPS);

  // ---- normalize from registers + write ----
  float* Ob = Out + (size_t)b * C_IN * N_PIX;
#pragma unroll
  for (int i = 0; i < 4; ++i) {
    const int rowb = m0 + mOff + i * 16 + kg * 4;
#pragma unroll
    for (int r = 0; r < 4; ++r) {
      const int ch = rowb + r;
      const float bvs = bias[ch];
      const float g = gamma[ch] * istd;
      const float be = beta[ch];
#pragma unroll
      for (int j = 0; j < 4; ++j) {
        const int col = n0 + nOff + j * 16 + lr;
        const float v = acc[i][j][r] + bvs;
        Ob[(size_t)ch * N_PIX + col] = (v - mean) * g + be;
      }
    }
  }
}

// ---------------------------------------------------------------------------
// Workspace (bytes):
//   qkv_bf : 50,331,648  (q channels unused; K/V only)
//   qsm_t  : 16,777,216
//   wq_bf  : 196,608   wo_bf : 65,536
//   ctxp   : 8,388,608   mpart/spart : 262,144 each
//   weff   : 1,048,576
//   gn_part: 8,192   bar: 128
// total ~77.3 MB
// ---------------------------------------------------------------------------
extern "C" void kernel_launch(void* const* d_in, const int* in_sizes, int n_in,
                              void* d_out, int out_size, void* d_ws, size_t ws_size,
                              hipStream_t stream) {
  const float* x = (const float*)d_in[0];
  const float* w_qkv = (const float*)d_in[1];
  const float* w_out = (const float*)d_in[2];
  const float* b_out = (const float*)d_in[3];
  const float* gamma = (const float*)d_in[4];
  const float* beta = (const float*)d_in[5];
  float* out = (float*)d_out;

  char* p = (char*)d_ws;
  unsigned short* qkv_bf = (unsigned short*)p; p += (size_t)B_SZ * QKV_CH * N_PIX * 2;
  unsigned short* qsm_t = (unsigned short*)p;  p += (size_t)B_SZ * N_PIX * INNER * 2;
  unsigned short* wq_bf = (unsigned short*)p;  p += (size_t)QKV_CH * C_IN * 2;
  unsigned short* wo_bf = (unsigned short*)p;  p += (size_t)C_IN * INNER * 2;
  float* ctxp = (float*)p;    p += (size_t)B_SZ * HEADS * NCHK * 1024 * 4;
  float* mpart = (float*)p;   p += (size_t)B_SZ * HEADS * NCHK * 32 * 4;
  float* spart = (float*)p;   p += (size_t)B_SZ * HEADS * NCHK * 32 * 4;
  unsigned short* weff = (unsigned short*)p; p += (size_t)B_SZ * C_IN * INNER * 2;
  float* gn_part = (float*)p; p += (size_t)1024 * 2 * 4;
  unsigned int* bar = (unsigned int*)p; p += 128;

  cvt_w<<<dim3(384), 256, 0, stream>>>(w_qkv, w_out, wq_bf, wo_bf, bar);
  qkv_gemm<<<dim3(64, B_SZ), 512, 0, stream>>>(wq_bf, x, qkv_bf, qsm_t);
  ctx_mfma<<<dim3(512), 256, 0, stream>>>(qkv_bf, ctxp, mpart, spart);
  ctx_weff<<<dim3(64), 256, 0, stream>>>(ctxp, mpart, spart, wo_bf, weff);
  out_full<<<dim3(1024), 256, 0, stream>>>(
      weff, qsm_t, out, b_out, gn_part, gamma, beta, bar);
}

// Round 19
// 82.875 us; speedup vs baseline: 1.7887x; 1.7887x over previous
//
#include <hip/hip_runtime.h>
#include <hip/hip_bf16.h>
#include <math.h>

#define B_SZ 16
#define C_IN 256
#define HEADS 4
#define DHEAD 32
#define INNER 128
#define QKV_CH 384
#define N_PIX 4096
#define SCALE_Q 0.17677669529663687f  // 32^-0.5
#define GN_EPS 1e-5f
#define NCHK 32  // ctx chunks of K=128

typedef __attribute__((ext_vector_type(8))) short s16x8;
typedef __attribute__((ext_vector_type(4))) float f32x4;
typedef __attribute__((ext_vector_type(8))) unsigned short u16x8;
typedef __attribute__((ext_vector_type(4))) unsigned short u16x4;

#define VMCNT(n) asm volatile("s_waitcnt vmcnt(" #n ")" ::: "memory")
#define LGKMCNT0 asm volatile("s_waitcnt lgkmcnt(0)" ::: "memory")

__device__ __forceinline__ float waveSum(float v) {
#pragma unroll
  for (int off = 32; off > 0; off >>= 1) v += __shfl_down(v, off, 64);
  return v;
}
__device__ __forceinline__ unsigned short f2bf(float f) {  // RNE
  unsigned int u = __builtin_bit_cast(unsigned int, f);
  unsigned int r = 0x7FFFu + ((u >> 16) & 1u);
  return (unsigned short)((u + r) >> 16);
}
__device__ __forceinline__ float bf2f(unsigned short u) {
  unsigned int x = ((unsigned int)u) << 16;
  return __builtin_bit_cast(float, x);
}

// ---------------------------------------------------------------------------
// K0: convert weights to bf16 (tiny)
// ---------------------------------------------------------------------------
__global__ __launch_bounds__(256) void cvt_w(const float* __restrict__ wq,
                                             const float* __restrict__ wo,
                                             unsigned short* __restrict__ wqb,
                                             unsigned short* __restrict__ wob) {
  const int i = blockIdx.x * 256 + threadIdx.x;
  if (i < QKV_CH * C_IN) wqb[i] = f2bf(wq[i]);
  if (i < C_IN * INNER) wob[i] = f2bf(wo[i]);
}

// ---------------------------------------------------------------------------
// K1: qkv GEMM — FROZEN r8 core (best of 10 structural variants, 41-52us
// band). 2D grid, no XCD swizzle (r7/r8 A/B: swizzle hot-spots HBM channels
// on this kernel). Fused q-softmax epilogue. launch_bounds(512,4): VGPR cap
// 128 (r6 lesson). Remaining headroom is latency-bound structure (all pipes
// <15%); producer-consumer wave specialization is the documented next step.
// ---------------------------------------------------------------------------
__global__ __launch_bounds__(512, 4) void qkv_gemm(const unsigned short* __restrict__ A,
                                                   const float* __restrict__ X,
                                                   unsigned short* __restrict__ Out,
                                                   unsigned short* __restrict__ qsm_t) {
  const int b = blockIdx.y;
  const int n0 = blockIdx.x * 64;
  const int tid = threadIdx.x;
  const int w = tid >> 6, l = tid & 63;
  const int lr = l & 15, kg = l >> 4;
  const int wm = w >> 1, wn = w & 1;  // 4M x 2N wave grid on (192, 64)

  __shared__ char lds[65536];
  char* As = lds;          // 2 x 24576 B : [half][192 m][64 c] bf16, swizzled
  char* Bs = lds + 49152;  // 2 x 8192 B  : [pb][64 n][64 c] bf16, swizzled

  const int c_loc = ((tid >> 3) & 7) + w * 8;  // 0..63 (c within chunk)
  const int oct = tid & 7;                     // n-octet
  const float* xbase = X + (size_t)b * C_IN * N_PIX + (size_t)c_loc * N_PIX + n0 + oct * 8;

  // ---- A stage: 3x global_load_lds (16B), dest linear, src pre-swizzled ----
  auto ISSUE_A = [&](int kc, int half) {
#pragma unroll
    for (int it = 0; it < 3; ++it) {
      const int idx = it * 512 + tid;
      const int r = idx >> 3;  // local m-row 0..191
      const int srcb = ((idx & 7) << 4) ^ ((r & 7) << 4);
      __builtin_amdgcn_global_load_lds(
          (const __attribute__((address_space(1))) void*)((const char*)A +
              ((size_t)(half * 192 + r) * C_IN + kc * 64) * 2 + srcb),
          (__attribute__((address_space(3))) void*)(As + half * 24576 + idx * 16), 16, 0, 0);
    }
  };

  f32x4 xr0, xr1;  // 8 fp32: x[c_loc][n0 + oct*8 .. +8)
  auto ISSUE_X = [&](int kc) {
    const float* xp = xbase + (size_t)(kc * 64) * N_PIX;
    xr0 = *reinterpret_cast<const f32x4*>(xp);
    xr1 = *reinterpret_cast<const f32x4*>(xp + 4);
  };

  auto WRITE_B = [&](int pb) {
#pragma unroll
    for (int j = 0; j < 8; ++j) {
      const int n = oct * 8 + j;
      const float v = (j < 4) ? xr0[j] : xr1[j - 4];
      *reinterpret_cast<unsigned short*>(
          Bs + pb * 8192 + n * 128 + ((2 * c_loc) ^ (((n ^ (n >> 3)) & 7) << 4))) = f2bf(v);
    }
  };

  f32x4 acc[2][3][2] = {};

  auto COMPUTE = [&](int kc, int half) {
    const char* Ab = As + half * 24576;
    const char* Bb = Bs + (kc & 1) * 8192;
#pragma unroll
    for (int ks = 0; ks < 2; ++ks) {
      const int kb = ks * 64 + kg * 16;
      s16x8 av[3], bv[2];
#pragma unroll
      for (int i = 0; i < 3; ++i) {
        const int r = wm * 48 + i * 16 + lr;
        av[i] = *reinterpret_cast<const s16x8*>(Ab + r * 128 + (kb ^ ((r & 7) << 4)));
      }
#pragma unroll
      for (int j = 0; j < 2; ++j) {
        const int n = wn * 32 + j * 16 + lr;
        bv[j] = *reinterpret_cast<const s16x8*>(Bb + n * 128 +
                                                (kb ^ (((n ^ (n >> 3)) & 7) << 4)));
      }
#pragma unroll
      for (int i = 0; i < 3; ++i)
#pragma unroll
        for (int j = 0; j < 2; ++j)
          acc[half][i][j] =
              __builtin_amdgcn_mfma_f32_16x16x32_bf16(av[i], bv[j], acc[half][i][j], 0, 0, 0);
    }
  };

  // ---- prologue ----
  ISSUE_A(0, 0);
  ISSUE_X(0);
  VMCNT(0);  // A(0,0) AND x(0) landed
  WRITE_B(0);
  LGKMCNT0;
  __builtin_amdgcn_s_barrier();  // As buf0 + Bs buf0 visible to all waves

  for (int kc = 0; kc < 4; ++kc) {
    // -- substep (kc,0): compute A-half0; prefetch A-half1 (+ next x) --
    ISSUE_A(kc, 1);
    if (kc < 3) {
      ISSUE_X(kc + 1);
      VMCNT(5);  // A(kc,0) (3 oldest) done
    } else {
      VMCNT(3);  // A(3,0) done
    }
    __builtin_amdgcn_s_barrier();  // RAW: all waves' A(kc,0) loads visible
    COMPUTE(kc, 0);
    LGKMCNT0;
    __builtin_amdgcn_s_barrier();  // WAR: buf0 free for next writer
    // -- substep (kc,1): compute A-half1; prefetch next A-half0; write next B --
    if (kc < 3) {
      ISSUE_A(kc + 1, 0);
      VMCNT(3);  // A(kc,1)+x(kc+1) done
    } else {
      VMCNT(0);
    }
    __builtin_amdgcn_s_barrier();  // RAW: all waves' A(kc,1) loads visible
    if (kc < 3) WRITE_B((kc + 1) & 1);
    COMPUTE(kc, 1);
    LGKMCNT0;
    __builtin_amdgcn_s_barrier();  // B visible; close half1 reads
  }
  // loop ends with all ds_reads drained + barrier -> LDS free for reuse

  // ---- epilogue part 1: K/V global stores (skip q channels m<128) ----
  unsigned short* Ob = Out + (size_t)b * QKV_CH * N_PIX;
#pragma unroll
  for (int half = 0; half < 2; ++half)
#pragma unroll
    for (int i = 0; i < 3; ++i) {
      const int mt = wm * 48 + i * 16;  // tile base within half
      if (half == 1 || mt >= 128) {
        const int mrow = half * 192 + mt + kg * 4;
#pragma unroll
        for (int j = 0; j < 2; ++j) {
          const int col = n0 + wn * 32 + j * 16 + lr;
#pragma unroll
          for (int r = 0; r < 4; ++r)
            Ob[(size_t)(mrow + r) * N_PIX + col] = f2bf(acc[half][i][j][r]);
        }
      }
    }

  // ---- epilogue part 2: stage q-acc (fp32) into LDS qs[64 n][132] ----
  float* qs = (float*)lds;  // 64*132*4 = 33792 B
#pragma unroll
  for (int i = 0; i < 3; ++i) {
    const int mt = wm * 48 + i * 16;
    if (mt < 128) {
      const int rowb = mt + kg * 4;
#pragma unroll
      for (int j = 0; j < 2; ++j) {
        const int c_l = wn * 32 + j * 16 + lr;
        *reinterpret_cast<f32x4*>(qs + c_l * 132 + rowb) = acc[0][i][j];
      }
    }
  }
  LGKMCNT0;
  __builtin_amdgcn_s_barrier();  // q panel visible

  // ---- epilogue part 3: softmax over d per (n, h); write qsm_t bf16 ----
  if (tid < 256) {
    const int n_loc = tid & 63, h = tid >> 6;  // wave-uniform h
    const float* qrow = qs + n_loc * 132 + h * 32;
    f32x4 qv[8];
#pragma unroll
    for (int c = 0; c < 8; ++c) qv[c] = *reinterpret_cast<const f32x4*>(qrow + c * 4);
    float m = qv[0][0];
#pragma unroll
    for (int c = 0; c < 8; ++c)
#pragma unroll
      for (int r = 0; r < 4; ++r) m = fmaxf(m, qv[c][r]);
    float e[32];
    float s = 0.f;
#pragma unroll
    for (int c = 0; c < 8; ++c)
#pragma unroll
      for (int r = 0; r < 4; ++r) {
        e[c * 4 + r] = __expf(qv[c][r] - m);
        s += e[c * 4 + r];
      }
    const float inv = SCALE_Q / s;
    unsigned short* ob = qsm_t + ((size_t)b * N_PIX + n0 + n_loc) * INNER + h * DHEAD;
#pragma unroll
    for (int d8 = 0; d8 < 4; ++d8) {
      u16x8 pk;
#pragma unroll
      for (int r = 0; r < 8; ++r) pk[r] = f2bf(e[d8 * 8 + r] * inv);
      *reinterpret_cast<u16x8*>(&ob[d8 * 8]) = pk;
    }
  }
}

// ---------------------------------------------------------------------------
// K2: ctx via MFMA, wave-per-(b,h,chunk). chunk = 128 n values.
// grid 512 (XCD-swizzled — r12 A/B: removal was worse; keep), block 256.
// ---------------------------------------------------------------------------
__global__ __launch_bounds__(256) void ctx_mfma(const unsigned short* __restrict__ qkv,
                                                float* __restrict__ ctxp,
                                                float* __restrict__ mpart,
                                                float* __restrict__ spart) {
  const int id = blockIdx.x;
  const int rank = (id & 7) * 64 + (id >> 3);  // XCD-contiguous
  const int wid = rank * 4 + (threadIdx.x >> 6);
  const int l = threadIdx.x & 63;
  const int b = wid >> 7;
  const int h = (wid >> 5) & 3;
  const int c = wid & 31;
  const int lr = l & 15, kg = l >> 4;
  const unsigned short* kb =
      qkv + ((size_t)b * QKV_CH + INNER + h * DHEAD) * N_PIX + c * 128 + kg * 8;
  const unsigned short* vb = kb + (size_t)INNER * N_PIX;

  u16x8 kf[2][4], vf[2][4];
#pragma unroll
  for (int dt = 0; dt < 2; ++dt)
#pragma unroll
    for (int ks = 0; ks < 4; ++ks) {
      kf[dt][ks] = *reinterpret_cast<const u16x8*>(kb + (size_t)(dt * 16 + lr) * N_PIX + ks * 32);
      vf[dt][ks] = *reinterpret_cast<const u16x8*>(vb + (size_t)(dt * 16 + lr) * N_PIX + ks * 32);
    }
  float kv[2][4][8];
  float m[2] = {-INFINITY, -INFINITY};
#pragma unroll
  for (int dt = 0; dt < 2; ++dt)
#pragma unroll
    for (int ks = 0; ks < 4; ++ks)
#pragma unroll
      for (int j = 0; j < 8; ++j) {
        kv[dt][ks][j] = bf2f(kf[dt][ks][j]);
        m[dt] = fmaxf(m[dt], kv[dt][ks][j]);
      }
#pragma unroll
  for (int dt = 0; dt < 2; ++dt) {
    m[dt] = fmaxf(m[dt], __shfl_xor(m[dt], 16, 64));
    m[dt] = fmaxf(m[dt], __shfl_xor(m[dt], 32, 64));
  }
  float s[2] = {0.f, 0.f};
  s16x8 ka[2][4];
#pragma unroll
  for (int dt = 0; dt < 2; ++dt)
#pragma unroll
    for (int ks = 0; ks < 4; ++ks)
#pragma unroll
      for (int j = 0; j < 8; ++j) {
        const float e = __expf(kv[dt][ks][j] - m[dt]);
        s[dt] += e;
        ka[dt][ks][j] = (short)f2bf(e);
      }
#pragma unroll
  for (int dt = 0; dt < 2; ++dt) {
    s[dt] += __shfl_xor(s[dt], 16, 64);
    s[dt] += __shfl_xor(s[dt], 32, 64);
  }
  f32x4 acc[2][2] = {};
#pragma unroll
  for (int ks = 0; ks < 4; ++ks)
#pragma unroll
    for (int dt = 0; dt < 2; ++dt)
#pragma unroll
      for (int et = 0; et < 2; ++et)
        acc[dt][et] = __builtin_amdgcn_mfma_f32_16x16x32_bf16(
            ka[dt][ks], __builtin_bit_cast(s16x8, vf[et][ks]), acc[dt][et], 0, 0, 0);

  float* cp = ctxp + (size_t)wid * 1024;
#pragma unroll
  for (int dt = 0; dt < 2; ++dt)
#pragma unroll
    for (int et = 0; et < 2; ++et)
#pragma unroll
      for (int r = 0; r < 4; ++r)
        cp[(dt * 16 + kg * 4 + r) * 32 + et * 16 + lr] = acc[dt][et][r];
  if (kg == 0) {
    mpart[wid * 32 + lr] = m[0];
    mpart[wid * 32 + 16 + lr] = m[1];
    spart[wid * 32 + lr] = s[0];
    spart[wid * 32 + 16 + lr] = s[1];
  }
}

// ---------------------------------------------------------------------------
// K3 (ctx_reduce + weff merged, latency-fixed r11): grid 64 = (b*4+h),
// block 256. Unrolled chunk loads (concurrent issue) + f32x4 LDS reads.
// ---------------------------------------------------------------------------
__global__ __launch_bounds__(256) void ctx_weff(const float* __restrict__ ctxp,
                                                const float* __restrict__ mpart,
                                                const float* __restrict__ spart,
                                                const unsigned short* __restrict__ wo,
                                                unsigned short* __restrict__ weff) {
  const int bh = blockIdx.x;
  const int b = bh >> 2, h = bh & 3;
  const int tid = threadIdx.x;
  __shared__ float ms[NCHK][32], ss[NCHK][32], fac[NCHK][32];
  __shared__ float inv_l[32];
  __shared__ float cf[1024];  // [d][e]
#pragma unroll
  for (int i = 0; i < 4; ++i) {
    const int idx = tid + i * 256;  // c*32+d
    ms[idx >> 5][idx & 31] = mpart[(size_t)bh * 1024 + idx];
    ss[idx >> 5][idx & 31] = spart[(size_t)bh * 1024 + idx];
  }
  __syncthreads();
  if (tid < 32) {
    const int d = tid;
    float M = -INFINITY;
#pragma unroll
    for (int c = 0; c < NCHK; ++c) M = fmaxf(M, ms[c][d]);
    float den = 0.f;
#pragma unroll
    for (int c = 0; c < NCHK; ++c) {
      const float f = __expf(ms[c][d] - M);
      fac[c][d] = f;
      den += f * ss[c][d];
    }
    inv_l[d] = 1.0f / den;
  }
  __syncthreads();
  const float* cp = ctxp + (size_t)bh * (NCHK * 1024);
  for (int i = 0; i < 4; ++i) {
    const int idx = tid + i * 256;  // d*32+e
    const int d = idx >> 5;
    float vals[NCHK];
#pragma unroll
    for (int c = 0; c < NCHK; ++c) vals[c] = cp[(size_t)c * 1024 + idx];
    float a = 0.f;
#pragma unroll
    for (int c = 0; c < NCHK; ++c) a += fac[c][d] * vals[c];
    cf[idx] = a * inv_l[d];
  }
  __syncthreads();

  // ---- Phase 2: w_eff for this (b,h); thread owns channel o = tid ----
  const int o = tid;
  float wr[32];
  const unsigned short* wp = wo + (size_t)o * INNER + h * DHEAD;
#pragma unroll
  for (int e8 = 0; e8 < 4; ++e8) {
    u16x8 v = *reinterpret_cast<const u16x8*>(wp + e8 * 8);
#pragma unroll
    for (int j = 0; j < 8; ++j) wr[e8 * 8 + j] = bf2f(v[j]);
  }
  unsigned short* op = weff + ((size_t)b * C_IN + o) * INNER + h * DHEAD;
#pragma unroll
  for (int d8 = 0; d8 < 4; ++d8) {
    u16x8 outv;
#pragma unroll
    for (int dd = 0; dd < 8; ++dd) {
      const float* cr = cf + (d8 * 8 + dd) * 32;
      float a = 0.f;
#pragma unroll
      for (int e4 = 0; e4 < 8; ++e4) {
        const f32x4 c4 = *reinterpret_cast<const f32x4*>(cr + e4 * 4);  // b128 bcast
#pragma unroll
        for (int j = 0; j < 4; ++j) a += wr[e4 * 4 + j] * c4[j];
      }
      outv[dd] = f2bf(a);
    }
    *reinterpret_cast<u16x8*>(op + d8 * 8) = outv;
  }
}

// ---------------------------------------------------------------------------
// K5a/K5b: out-proj MFMA GEMM (A = per-batch w_eff), template two-pass GN.
// grid 1024 (XCD-swizzled — r12 A/B: keep), block 256. The two-pass GEMM
// redo (~8us) is cheaper than any grid-sync on this part: cooperative launch
// no-ops under graph capture (r9); software barrier spin storms the
// non-coherent XCD L2s (r18: out_full 70us vs 23us for this pair).
// rank = b*64 + mhalf*32 + ntile  (== gn_part slot, same in both passes).
// ---------------------------------------------------------------------------
template <bool WRITE>
__global__ __launch_bounds__(256) void out_gemm_t(
    const unsigned short* __restrict__ A, const unsigned short* __restrict__ Bm,
    float* __restrict__ Out, const float* __restrict__ bias,
    float* __restrict__ gn_part, const float* __restrict__ gamma,
    const float* __restrict__ beta) {
  const int id = blockIdx.x;
  const int rank = (id & 7) * 128 + (id >> 3);  // XCD-contiguous
  const int b = rank >> 6;
  const int m0 = ((rank >> 5) & 1) * 128;
  const int n0 = (rank & 31) * 128;
  const int tid = threadIdx.x;
  const int w = tid >> 6, l = tid & 63;
  const int lr = l & 15, kg = l >> 4;
  const int mOff = (w >> 1) * 64, nOff = (w & 1) * 64;

  __shared__ unsigned short As[8192];
  __shared__ unsigned short Bs[8192];
  __shared__ float red[8];

  const unsigned short* Ab = A + (size_t)b * C_IN * INNER;  // per-batch w_eff
  const unsigned short* Bb = Bm + (size_t)b * N_PIX * INNER;
  f32x4 acc[4][4] = {};

  for (int kc = 0; kc < INNER; kc += 64) {
#pragma unroll
    for (int s = 0; s < 4; ++s) {
      const int blk = (w * 4 + s) * 64 + l;
      const int r = blk >> 3;
      const int c = ((blk & 7) ^ (r & 7)) << 3;
      __builtin_amdgcn_global_load_lds(
          (const __attribute__((address_space(1))) void*)(Ab + (size_t)(m0 + r) * INNER + kc + c),
          (__attribute__((address_space(3))) void*)((char*)As + (w * 4 + s) * 1024), 16, 0, 0);
      __builtin_amdgcn_global_load_lds(
          (const __attribute__((address_space(1))) void*)(Bb + (size_t)(n0 + r) * INNER + kc + c),
          (__attribute__((address_space(3))) void*)((char*)Bs + (w * 4 + s) * 1024), 16, 0, 0);
    }
    __syncthreads();
#pragma unroll
    for (int ks = 0; ks < 2; ++ks) {
      const int kbyte = ks * 64 + kg * 16;
      s16x8 av[4], bv[4];
#pragma unroll
      for (int i = 0; i < 4; ++i) {
        const int row = mOff + i * 16 + lr;
        av[i] = *reinterpret_cast<const s16x8*>(
            (const char*)As + row * 128 + (kbyte ^ ((row & 7) << 4)));
      }
#pragma unroll
      for (int j = 0; j < 4; ++j) {
        const int row = nOff + j * 16 + lr;
        bv[j] = *reinterpret_cast<const s16x8*>(
            (const char*)Bs + row * 128 + (kbyte ^ ((row & 7) << 4)));
      }
#pragma unroll
      for (int i = 0; i < 4; ++i)
#pragma unroll
        for (int j = 0; j < 4; ++j)
          acc[i][j] = __builtin_amdgcn_mfma_f32_16x16x32_bf16(av[i], bv[j], acc[i][j], 0, 0, 0);
    }
    __syncthreads();
  }

  if (!WRITE) {
    float s = 0.f, s2 = 0.f;
#pragma unroll
    for (int i = 0; i < 4; ++i) {
      const int rowb = m0 + mOff + i * 16 + kg * 4;
#pragma unroll
      for (int r = 0; r < 4; ++r) {
        const float bvs = bias[rowb + r];
#pragma unroll
        for (int j = 0; j < 4; ++j) {
          const float v = acc[i][j][r] + bvs;
          s += v;
          s2 += v * v;
        }
      }
    }
    const float S = waveSum(s), S2 = waveSum(s2);
    if (l == 0) {
      red[w] = S;
      red[4 + w] = S2;
    }
    __syncthreads();
    if (tid == 0) {
      gn_part[(size_t)rank * 2 + 0] = red[0] + red[1] + red[2] + red[3];
      gn_part[(size_t)rank * 2 + 1] = red[4] + red[5] + red[6] + red[7];
    }
  } else {
    const int i64 = tid & 63;
    float ps = gn_part[(size_t)(b * 64 + i64) * 2 + 0];
    float ps2 = gn_part[(size_t)(b * 64 + i64) * 2 + 1];
    ps = waveSum(ps);
    ps2 = waveSum(ps2);
    const float invn = 1.0f / (float)(C_IN * N_PIX);
    const float mean = __shfl(ps, 0, 64) * invn;
    const float var = __shfl(ps2, 0, 64) * invn - mean * mean;
    const float istd = rsqrtf(var + GN_EPS);

    float* Ob = Out + (size_t)b * C_IN * N_PIX;
#pragma unroll
    for (int i = 0; i < 4; ++i) {
      const int rowb = m0 + mOff + i * 16 + kg * 4;
#pragma unroll
      for (int r = 0; r < 4; ++r) {
        const int ch = rowb + r;
        const float bvs = bias[ch];
        const float g = gamma[ch] * istd;
        const float be = beta[ch];
#pragma unroll
        for (int j = 0; j < 4; ++j) {
          const int col = n0 + nOff + j * 16 + lr;
          const float v = acc[i][j][r] + bvs;
          Ob[(size_t)ch * N_PIX + col] = (v - mean) * g + be;
        }
      }
    }
  }
}

// ---------------------------------------------------------------------------
// Workspace (bytes):
//   qkv_bf : 50,331,648  (q channels unused; K/V only)
//   qsm_t  : 16,777,216
//   wq_bf  : 196,608   wo_bf : 65,536
//   ctxp   : 8,388,608   mpart/spart : 262,144 each
//   weff   : 1,048,576
//   gn_part: 8,192
// total ~77.3 MB
// ---------------------------------------------------------------------------
extern "C" void kernel_launch(void* const* d_in, const int* in_sizes, int n_in,
                              void* d_out, int out_size, void* d_ws, size_t ws_size,
                              hipStream_t stream) {
  const float* x = (const float*)d_in[0];
  const float* w_qkv = (const float*)d_in[1];
  const float* w_out = (const float*)d_in[2];
  const float* b_out = (const float*)d_in[3];
  const float* gamma = (const float*)d_in[4];
  const float* beta = (const float*)d_in[5];
  float* out = (float*)d_out;

  char* p = (char*)d_ws;
  unsigned short* qkv_bf = (unsigned short*)p; p += (size_t)B_SZ * QKV_CH * N_PIX * 2;
  unsigned short* qsm_t = (unsigned short*)p;  p += (size_t)B_SZ * N_PIX * INNER * 2;
  unsigned short* wq_bf = (unsigned short*)p;  p += (size_t)QKV_CH * C_IN * 2;
  unsigned short* wo_bf = (unsigned short*)p;  p += (size_t)C_IN * INNER * 2;
  float* ctxp = (float*)p;    p += (size_t)B_SZ * HEADS * NCHK * 1024 * 4;
  float* mpart = (float*)p;   p += (size_t)B_SZ * HEADS * NCHK * 32 * 4;
  float* spart = (float*)p;   p += (size_t)B_SZ * HEADS * NCHK * 32 * 4;
  unsigned short* weff = (unsigned short*)p; p += (size_t)B_SZ * C_IN * INNER * 2;
  float* gn_part = (float*)p; p += (size_t)1024 * 2 * 4;

  cvt_w<<<dim3(384), 256, 0, stream>>>(w_qkv, w_out, wq_bf, wo_bf);
  qkv_gemm<<<dim3(64, B_SZ), 512, 0, stream>>>(wq_bf, x, qkv_bf, qsm_t);
  ctx_mfma<<<dim3(512), 256, 0, stream>>>(qkv_bf, ctxp, mpart, spart);
  ctx_weff<<<dim3(64), 256, 0, stream>>>(ctxp, mpart, spart, wo_bf, weff);
  out_gemm_t<false><<<dim3(1024), 256, 0, stream>>>(
      weff, qsm_t, nullptr, b_out, gn_part, nullptr, nullptr);
  out_gemm_t<true><<<dim3(1024), 256, 0, stream>>>(
      weff, qsm_t, out, b_out, gn_part, gamma, beta);
}

// Round 20
// 79.683 us; speedup vs baseline: 1.8604x; 1.0401x over previous
//
#include <hip/hip_runtime.h>
#include <hip/hip_bf16.h>
#include <math.h>

#define B_SZ 16
#define C_IN 256
#define HEADS 4
#define DHEAD 32
#define INNER 128
#define QKV_CH 384
#define N_PIX 4096
#define SCALE_Q 0.17677669529663687f  // 32^-0.5
#define GN_EPS 1e-5f
#define NCHK 64  // ctx chunks of 64 px (fused into qkv blocks)

#define KOFF 16896  // q region: [64 n][132 ch] u16 = 16896 B
#define VOFF 34304  // K region: [128 ch][68 n] u16 = 17408 B; V same

typedef __attribute__((ext_vector_type(8))) short s16x8;
typedef __attribute__((ext_vector_type(4))) float f32x4;
typedef __attribute__((ext_vector_type(8))) unsigned short u16x8;
typedef __attribute__((ext_vector_type(4))) unsigned short u16x4;

#define VMCNT(n) asm volatile("s_waitcnt vmcnt(" #n ")" ::: "memory")
#define LGKMCNT0 asm volatile("s_waitcnt lgkmcnt(0)" ::: "memory")

__device__ __forceinline__ float waveSum(float v) {
#pragma unroll
  for (int off = 32; off > 0; off >>= 1) v += __shfl_down(v, off, 64);
  return v;
}
__device__ __forceinline__ unsigned short f2bf(float f) {  // RNE
  unsigned int u = __builtin_bit_cast(unsigned int, f);
  unsigned int r = 0x7FFFu + ((u >> 16) & 1u);
  return (unsigned short)((u + r) >> 16);
}
__device__ __forceinline__ float bf2f(unsigned short u) {
  unsigned int x = ((unsigned int)u) << 16;
  return __builtin_bit_cast(float, x);
}

// ---------------------------------------------------------------------------
// K0: convert weights to bf16 (tiny)
// ---------------------------------------------------------------------------
__global__ __launch_bounds__(256) void cvt_w(const float* __restrict__ wq,
                                             const float* __restrict__ wo,
                                             unsigned short* __restrict__ wqb,
                                             unsigned short* __restrict__ wob) {
  const int i = blockIdx.x * 256 + threadIdx.x;
  if (i < QKV_CH * C_IN) wqb[i] = f2bf(wq[i]);
  if (i < C_IN * INNER) wob[i] = f2bf(wo[i]);
}

// ---------------------------------------------------------------------------
// K1: qkv GEMM (frozen r8 core) + FUSED q-softmax AND per-chunk ctx partial.
// The block holds all 384 channels for its 64 px -> K/V never touch global:
// stage q/K/V bf16 into the freed 64KB LDS (one barrier; all later phases
// read-only), then (a) tid<256 does q-softmax -> qsm_t, (b) 8 waves compute
// the ctx_mfma math for THIS 64-px chunk (NCHK=64): wave w -> head w>>1,
// et=w&1; fragment layouts copied 1:1 from the old ctx_mfma. Eliminates
// qkv_bf (33MB writes + 33MB reads) and the ctx_mfma dispatch.
// LDS: q [64][132]u16 (n-major, b64 stage/read); K,V [128][68]u16
// (ch-major, b16 stage, b64 fragment reads; 136B row = 8B aligned).
// ---------------------------------------------------------------------------
__global__ __launch_bounds__(512, 4) void qkv_gemm(const unsigned short* __restrict__ A,
                                                   const float* __restrict__ X,
                                                   unsigned short* __restrict__ qsm_t,
                                                   float* __restrict__ ctxp,
                                                   float* __restrict__ mpart,
                                                   float* __restrict__ spart) {
  const int b = blockIdx.y;
  const int n0 = blockIdx.x * 64;
  const int tid = threadIdx.x;
  const int w = tid >> 6, l = tid & 63;
  const int lr = l & 15, kg = l >> 4;
  const int wm = w >> 1, wn = w & 1;  // 4M x 2N wave grid on (192, 64)

  __shared__ char lds[65536];
  char* As = lds;          // 2 x 24576 B : [half][192 m][64 c] bf16, swizzled
  char* Bs = lds + 49152;  // 2 x 8192 B  : [pb][64 n][64 c] bf16, swizzled

  const int c_loc = ((tid >> 3) & 7) + w * 8;  // 0..63 (c within chunk)
  const int oct = tid & 7;                     // n-octet
  const float* xbase = X + (size_t)b * C_IN * N_PIX + (size_t)c_loc * N_PIX + n0 + oct * 8;

  // ---- A stage: 3x global_load_lds (16B), dest linear, src pre-swizzled ----
  auto ISSUE_A = [&](int kc, int half) {
#pragma unroll
    for (int it = 0; it < 3; ++it) {
      const int idx = it * 512 + tid;
      const int r = idx >> 3;  // local m-row 0..191
      const int srcb = ((idx & 7) << 4) ^ ((r & 7) << 4);
      __builtin_amdgcn_global_load_lds(
          (const __attribute__((address_space(1))) void*)((const char*)A +
              ((size_t)(half * 192 + r) * C_IN + kc * 64) * 2 + srcb),
          (__attribute__((address_space(3))) void*)(As + half * 24576 + idx * 16), 16, 0, 0);
    }
  };

  f32x4 xr0, xr1;  // 8 fp32: x[c_loc][n0 + oct*8 .. +8)
  auto ISSUE_X = [&](int kc) {
    const float* xp = xbase + (size_t)(kc * 64) * N_PIX;
    xr0 = *reinterpret_cast<const f32x4*>(xp);
    xr1 = *reinterpret_cast<const f32x4*>(xp + 4);
  };

  auto WRITE_B = [&](int pb) {
#pragma unroll
    for (int j = 0; j < 8; ++j) {
      const int n = oct * 8 + j;
      const float v = (j < 4) ? xr0[j] : xr1[j - 4];
      *reinterpret_cast<unsigned short*>(
          Bs + pb * 8192 + n * 128 + ((2 * c_loc) ^ (((n ^ (n >> 3)) & 7) << 4))) = f2bf(v);
    }
  };

  f32x4 acc[2][3][2] = {};

  auto COMPUTE = [&](int kc, int half) {
    const char* Ab = As + half * 24576;
    const char* Bb = Bs + (kc & 1) * 8192;
#pragma unroll
    for (int ks = 0; ks < 2; ++ks) {
      const int kb = ks * 64 + kg * 16;
      s16x8 av[3], bv[2];
#pragma unroll
      for (int i = 0; i < 3; ++i) {
        const int r = wm * 48 + i * 16 + lr;
        av[i] = *reinterpret_cast<const s16x8*>(Ab + r * 128 + (kb ^ ((r & 7) << 4)));
      }
#pragma unroll
      for (int j = 0; j < 2; ++j) {
        const int n = wn * 32 + j * 16 + lr;
        bv[j] = *reinterpret_cast<const s16x8*>(Bb + n * 128 +
                                                (kb ^ (((n ^ (n >> 3)) & 7) << 4)));
      }
#pragma unroll
      for (int i = 0; i < 3; ++i)
#pragma unroll
        for (int j = 0; j < 2; ++j)
          acc[half][i][j] =
              __builtin_amdgcn_mfma_f32_16x16x32_bf16(av[i], bv[j], acc[half][i][j], 0, 0, 0);
    }
  };

  // ---- prologue ----
  ISSUE_A(0, 0);
  ISSUE_X(0);
  VMCNT(0);  // A(0,0) AND x(0) landed
  WRITE_B(0);
  LGKMCNT0;
  __builtin_amdgcn_s_barrier();  // As buf0 + Bs buf0 visible to all waves

  for (int kc = 0; kc < 4; ++kc) {
    ISSUE_A(kc, 1);
    if (kc < 3) {
      ISSUE_X(kc + 1);
      VMCNT(5);  // A(kc,0) (3 oldest) done
    } else {
      VMCNT(3);  // A(3,0) done
    }
    __builtin_amdgcn_s_barrier();  // RAW: all waves' A(kc,0) loads visible
    COMPUTE(kc, 0);
    LGKMCNT0;
    __builtin_amdgcn_s_barrier();  // WAR: buf0 free for next writer
    if (kc < 3) {
      ISSUE_A(kc + 1, 0);
      VMCNT(3);  // A(kc,1)+x(kc+1) done
    } else {
      VMCNT(0);
    }
    __builtin_amdgcn_s_barrier();  // RAW: all waves' A(kc,1) loads visible
    if (kc < 3) WRITE_B((kc + 1) & 1);
    COMPUTE(kc, 1);
    LGKMCNT0;
    __builtin_amdgcn_s_barrier();  // B visible; close half1 reads
  }
  // main loop done: all LDS reads drained + barrier -> LDS free for reuse

  // ---- epilogue stage: q (n-major) + K/V (ch-major) as bf16 into LDS ----
#pragma unroll
  for (int half = 0; half < 2; ++half)
#pragma unroll
    for (int i = 0; i < 3; ++i)
#pragma unroll
      for (int j = 0; j < 2; ++j) {
        const int chb = half * 192 + wm * 48 + i * 16 + kg * 4;  // mult of 4
        const int col = wn * 32 + j * 16 + lr;
        u16x4 pk;
#pragma unroll
        for (int r = 0; r < 4; ++r) pk[r] = f2bf(acc[half][i][j][r]);
        if (chb < 128) {
          *reinterpret_cast<u16x4*>(lds + col * 264 + chb * 2) = pk;  // 8B-aligned
        } else if (chb < 256) {
#pragma unroll
          for (int r = 0; r < 4; ++r)
            *reinterpret_cast<unsigned short*>(lds + KOFF + (chb - 128 + r) * 136 + col * 2) =
                pk[r];
        } else {
#pragma unroll
          for (int r = 0; r < 4; ++r)
            *reinterpret_cast<unsigned short*>(lds + VOFF + (chb - 256 + r) * 136 + col * 2) =
                pk[r];
        }
      }
  LGKMCNT0;
  __builtin_amdgcn_s_barrier();  // staging visible; all later LDS use is read-only

  // ---- phase A: q-softmax (tid<256), write qsm_t ----
  if (tid < 256) {
    const int n_loc = tid & 63, h2 = tid >> 6;
    float q[32];
#pragma unroll
    for (int c = 0; c < 8; ++c) {
      u16x4 v4 = *reinterpret_cast<const u16x4*>(lds + n_loc * 264 + h2 * 64 + c * 8);
#pragma unroll
      for (int t = 0; t < 4; ++t) q[c * 4 + t] = bf2f(v4[t]);
    }
    float m = q[0];
#pragma unroll
    for (int t = 1; t < 32; ++t) m = fmaxf(m, q[t]);
    float s = 0.f;
#pragma unroll
    for (int t = 0; t < 32; ++t) {
      q[t] = __expf(q[t] - m);
      s += q[t];
    }
    const float inv = SCALE_Q / s;
    unsigned short* ob = qsm_t + ((size_t)b * N_PIX + n0 + n_loc) * INNER + h2 * DHEAD;
#pragma unroll
    for (int d8 = 0; d8 < 4; ++d8) {
      u16x8 pk;
#pragma unroll
      for (int r = 0; r < 8; ++r) pk[r] = f2bf(q[d8 * 8 + r] * inv);
      *reinterpret_cast<u16x8*>(&ob[d8 * 8]) = pk;
    }
  }

  // ---- phase B: ctx partial for this 64-px chunk (layouts = old ctx_mfma) ----
  {
    const int h = w >> 1, et = w & 1;
    float kvv[2][2][8];  // [dt][ks][t]: K[h*32+dt*16+lr][ks*32+kg*8+t]
#pragma unroll
    for (int dt = 0; dt < 2; ++dt)
#pragma unroll
      for (int ks = 0; ks < 2; ++ks) {
        const char* base = lds + KOFF + (h * 32 + dt * 16 + lr) * 136 + (ks * 32 + kg * 8) * 2;
        u16x4 lo = *reinterpret_cast<const u16x4*>(base);
        u16x4 hi = *reinterpret_cast<const u16x4*>(base + 8);
#pragma unroll
        for (int t = 0; t < 4; ++t) {
          kvv[dt][ks][t] = bf2f(lo[t]);
          kvv[dt][ks][4 + t] = bf2f(hi[t]);
        }
      }
    float m2[2] = {-INFINITY, -INFINITY};
#pragma unroll
    for (int dt = 0; dt < 2; ++dt) {
#pragma unroll
      for (int ks = 0; ks < 2; ++ks)
#pragma unroll
        for (int t = 0; t < 8; ++t) m2[dt] = fmaxf(m2[dt], kvv[dt][ks][t]);
      m2[dt] = fmaxf(m2[dt], __shfl_xor(m2[dt], 16, 64));
      m2[dt] = fmaxf(m2[dt], __shfl_xor(m2[dt], 32, 64));
    }
    float s2[2] = {0.f, 0.f};
    s16x8 ka[2][2];
#pragma unroll
    for (int dt = 0; dt < 2; ++dt) {
#pragma unroll
      for (int ks = 0; ks < 2; ++ks)
#pragma unroll
        for (int t = 0; t < 8; ++t) {
          const float ev = __expf(kvv[dt][ks][t] - m2[dt]);
          s2[dt] += ev;
          ka[dt][ks][t] = (short)f2bf(ev);
        }
      s2[dt] += __shfl_xor(s2[dt], 16, 64);
      s2[dt] += __shfl_xor(s2[dt], 32, 64);
    }
    s16x8 vfrag[2];  // V[h*32+et*16+lr][ks*32+kg*8+t]
#pragma unroll
    for (int ks = 0; ks < 2; ++ks) {
      const char* base = lds + VOFF + (h * 32 + et * 16 + lr) * 136 + (ks * 32 + kg * 8) * 2;
      u16x4 lo = *reinterpret_cast<const u16x4*>(base);
      u16x4 hi = *reinterpret_cast<const u16x4*>(base + 8);
      u16x8 vv;
#pragma unroll
      for (int t = 0; t < 4; ++t) {
        vv[t] = lo[t];
        vv[4 + t] = hi[t];
      }
      vfrag[ks] = __builtin_bit_cast(s16x8, vv);
    }
    f32x4 accc[2] = {};
#pragma unroll
    for (int ks = 0; ks < 2; ++ks)
#pragma unroll
      for (int dt = 0; dt < 2; ++dt)
        accc[dt] = __builtin_amdgcn_mfma_f32_16x16x32_bf16(ka[dt][ks], vfrag[ks], accc[dt], 0, 0, 0);

    const size_t wid = ((size_t)(b * HEADS + h)) * NCHK + blockIdx.x;
    float* cp = ctxp + wid * 1024;
#pragma unroll
    for (int dt = 0; dt < 2; ++dt)
#pragma unroll
      for (int r = 0; r < 4; ++r)
        cp[(dt * 16 + kg * 4 + r) * 32 + et * 16 + lr] = accc[dt][r];
    if (et == 0 && kg == 0) {
      mpart[wid * 32 + lr] = m2[0];
      mpart[wid * 32 + 16 + lr] = m2[1];
      spart[wid * 32 + lr] = s2[0];
      spart[wid * 32 + 16 + lr] = s2[1];
    }
  }
}

// ---------------------------------------------------------------------------
// K3 (ctx_reduce + weff merged), NCHK=64: grid 64 = (b*4+h), block 256.
// Chunk-sum split into 2x32 unrolled load batches (VGPR cap).
// ---------------------------------------------------------------------------
__global__ __launch_bounds__(256) void ctx_weff(const float* __restrict__ ctxp,
                                                const float* __restrict__ mpart,
                                                const float* __restrict__ spart,
                                                const unsigned short* __restrict__ wo,
                                                unsigned short* __restrict__ weff) {
  const int bh = blockIdx.x;
  const int b = bh >> 2, h = bh & 3;
  const int tid = threadIdx.x;
  __shared__ float ms[NCHK][32], ss[NCHK][32], fac[NCHK][32];  // 3 x 8KB
  __shared__ float inv_l[32];
  __shared__ float cf[1024];  // [d][e]
#pragma unroll
  for (int i = 0; i < 8; ++i) {
    const int idx = tid + i * 256;  // c*32+d, 2048 total
    ms[idx >> 5][idx & 31] = mpart[(size_t)bh * 2048 + idx];
    ss[idx >> 5][idx & 31] = spart[(size_t)bh * 2048 + idx];
  }
  __syncthreads();
  if (tid < 32) {
    const int d = tid;
    float M = -INFINITY;
#pragma unroll
    for (int c = 0; c < NCHK; ++c) M = fmaxf(M, ms[c][d]);
    float den = 0.f;
#pragma unroll
    for (int c = 0; c < NCHK; ++c) {
      const float f = __expf(ms[c][d] - M);
      fac[c][d] = f;
      den += f * ss[c][d];
    }
    inv_l[d] = 1.0f / den;
  }
  __syncthreads();
  const float* cp = ctxp + (size_t)bh * (NCHK * 1024);
  for (int i = 0; i < 4; ++i) {
    const int idx = tid + i * 256;  // d*32+e
    const int d = idx >> 5;
    float a = 0.f;
#pragma unroll
    for (int g = 0; g < 2; ++g) {
      float vals[32];
#pragma unroll
      for (int c = 0; c < 32; ++c) vals[c] = cp[(size_t)(g * 32 + c) * 1024 + idx];
#pragma unroll
      for (int c = 0; c < 32; ++c) a += fac[g * 32 + c][d] * vals[c];
    }
    cf[idx] = a * inv_l[d];
  }
  __syncthreads();

  // ---- Phase 2: w_eff for this (b,h); thread owns channel o = tid ----
  const int o = tid;
  float wr[32];
  const unsigned short* wp = wo + (size_t)o * INNER + h * DHEAD;
#pragma unroll
  for (int e8 = 0; e8 < 4; ++e8) {
    u16x8 v = *reinterpret_cast<const u16x8*>(wp + e8 * 8);
#pragma unroll
    for (int j = 0; j < 8; ++j) wr[e8 * 8 + j] = bf2f(v[j]);
  }
  unsigned short* op = weff + ((size_t)b * C_IN + o) * INNER + h * DHEAD;
#pragma unroll
  for (int d8 = 0; d8 < 4; ++d8) {
    u16x8 outv;
#pragma unroll
    for (int dd = 0; dd < 8; ++dd) {
      const float* cr = cf + (d8 * 8 + dd) * 32;
      float a = 0.f;
#pragma unroll
      for (int e4 = 0; e4 < 8; ++e4) {
        const f32x4 c4 = *reinterpret_cast<const f32x4*>(cr + e4 * 4);  // b128 bcast
#pragma unroll
        for (int j = 0; j < 4; ++j) a += wr[e4 * 4 + j] * c4[j];
      }
      outv[dd] = f2bf(a);
    }
    *reinterpret_cast<u16x8*>(op + d8 * 8) = outv;
  }
}

// ---------------------------------------------------------------------------
// K5a/K5b: out-proj MFMA GEMM (A = per-batch w_eff), template two-pass GN.
// grid 1024 (XCD-swizzled), block 256. Two-pass redo (~8us) is cheaper than
// any grid-sync on this part (r9 coop no-op; r18 sw-barrier 70us).
// rank = b*64 + mhalf*32 + ntile  (== gn_part slot, same in both passes).
// ---------------------------------------------------------------------------
template <bool WRITE>
__global__ __launch_bounds__(256) void out_gemm_t(
    const unsigned short* __restrict__ A, const unsigned short* __restrict__ Bm,
    float* __restrict__ Out, const float* __restrict__ bias,
    float* __restrict__ gn_part, const float* __restrict__ gamma,
    const float* __restrict__ beta) {
  const int id = blockIdx.x;
  const int rank = (id & 7) * 128 + (id >> 3);  // XCD-contiguous
  const int b = rank >> 6;
  const int m0 = ((rank >> 5) & 1) * 128;
  const int n0 = (rank & 31) * 128;
  const int tid = threadIdx.x;
  const int w = tid >> 6, l = tid & 63;
  const int lr = l & 15, kg = l >> 4;
  const int mOff = (w >> 1) * 64, nOff = (w & 1) * 64;

  __shared__ unsigned short As[8192];
  __shared__ unsigned short Bs[8192];
  __shared__ float red[8];

  const unsigned short* Ab = A + (size_t)b * C_IN * INNER;  // per-batch w_eff
  const unsigned short* Bb = Bm + (size_t)b * N_PIX * INNER;
  f32x4 acc[4][4] = {};

  for (int kc = 0; kc < INNER; kc += 64) {
#pragma unroll
    for (int s = 0; s < 4; ++s) {
      const int blk = (w * 4 + s) * 64 + l;
      const int r = blk >> 3;
      const int c = ((blk & 7) ^ (r & 7)) << 3;
      __builtin_amdgcn_global_load_lds(
          (const __attribute__((address_space(1))) void*)(Ab + (size_t)(m0 + r) * INNER + kc + c),
          (__attribute__((address_space(3))) void*)((char*)As + (w * 4 + s) * 1024), 16, 0, 0);
      __builtin_amdgcn_global_load_lds(
          (const __attribute__((address_space(1))) void*)(Bb + (size_t)(n0 + r) * INNER + kc + c),
          (__attribute__((address_space(3))) void*)((char*)Bs + (w * 4 + s) * 1024), 16, 0, 0);
    }
    __syncthreads();
#pragma unroll
    for (int ks = 0; ks < 2; ++ks) {
      const int kbyte = ks * 64 + kg * 16;
      s16x8 av[4], bv[4];
#pragma unroll
      for (int i = 0; i < 4; ++i) {
        const int row = mOff + i * 16 + lr;
        av[i] = *reinterpret_cast<const s16x8*>(
            (const char*)As + row * 128 + (kbyte ^ ((row & 7) << 4)));
      }
#pragma unroll
      for (int j = 0; j < 4; ++j) {
        const int row = nOff + j * 16 + lr;
        bv[j] = *reinterpret_cast<const s16x8*>(
            (const char*)Bs + row * 128 + (kbyte ^ ((row & 7) << 4)));
      }
#pragma unroll
      for (int i = 0; i < 4; ++i)
#pragma unroll
        for (int j = 0; j < 4; ++j)
          acc[i][j] = __builtin_amdgcn_mfma_f32_16x16x32_bf16(av[i], bv[j], acc[i][j], 0, 0, 0);
    }
    __syncthreads();
  }

  if (!WRITE) {
    float s = 0.f, s2 = 0.f;
#pragma unroll
    for (int i = 0; i < 4; ++i) {
      const int rowb = m0 + mOff + i * 16 + kg * 4;
#pragma unroll
      for (int r = 0; r < 4; ++r) {
        const float bvs = bias[rowb + r];
#pragma unroll
        for (int j = 0; j < 4; ++j) {
          const float v = acc[i][j][r] + bvs;
          s += v;
          s2 += v * v;
        }
      }
    }
    const float S = waveSum(s), S2 = waveSum(s2);
    if (l == 0) {
      red[w] = S;
      red[4 + w] = S2;
    }
    __syncthreads();
    if (tid == 0) {
      gn_part[(size_t)rank * 2 + 0] = red[0] + red[1] + red[2] + red[3];
      gn_part[(size_t)rank * 2 + 1] = red[4] + red[5] + red[6] + red[7];
    }
  } else {
    const int i64 = tid & 63;
    float ps = gn_part[(size_t)(b * 64 + i64) * 2 + 0];
    float ps2 = gn_part[(size_t)(b * 64 + i64) * 2 + 1];
    ps = waveSum(ps);
    ps2 = waveSum(ps2);
    const float invn = 1.0f / (float)(C_IN * N_PIX);
    const float mean = __shfl(ps, 0, 64) * invn;
    const float var = __shfl(ps2, 0, 64) * invn - mean * mean;
    const float istd = rsqrtf(var + GN_EPS);

    float* Ob = Out + (size_t)b * C_IN * N_PIX;
#pragma unroll
    for (int i = 0; i < 4; ++i) {
      const int rowb = m0 + mOff + i * 16 + kg * 4;
#pragma unroll
      for (int r = 0; r < 4; ++r) {
        const int ch = rowb + r;
        const float bvs = bias[ch];
        const float g = gamma[ch] * istd;
        const float be = beta[ch];
#pragma unroll
        for (int j = 0; j < 4; ++j) {
          const int col = n0 + nOff + j * 16 + lr;
          const float v = acc[i][j][r] + bvs;
          Ob[(size_t)ch * N_PIX + col] = (v - mean) * g + be;
        }
      }
    }
  }
}

// ---------------------------------------------------------------------------
// Workspace (bytes):
//   qsm_t  : 16,777,216
//   wq_bf  : 196,608   wo_bf : 65,536
//   ctxp   : 16,777,216   mpart/spart : 524,288 each
//   weff   : 1,048,576
//   gn_part: 8,192
// total ~36 MB (qkv_bf eliminated)
// ---------------------------------------------------------------------------
extern "C" void kernel_launch(void* const* d_in, const int* in_sizes, int n_in,
                              void* d_out, int out_size, void* d_ws, size_t ws_size,
                              hipStream_t stream) {
  const float* x = (const float*)d_in[0];
  const float* w_qkv = (const float*)d_in[1];
  const float* w_out = (const float*)d_in[2];
  const float* b_out = (const float*)d_in[3];
  const float* gamma = (const float*)d_in[4];
  const float* beta = (const float*)d_in[5];
  float* out = (float*)d_out;

  char* p = (char*)d_ws;
  unsigned short* qsm_t = (unsigned short*)p; p += (size_t)B_SZ * N_PIX * INNER * 2;
  unsigned short* wq_bf = (unsigned short*)p; p += (size_t)QKV_CH * C_IN * 2;
  unsigned short* wo_bf = (unsigned short*)p; p += (size_t)C_IN * INNER * 2;
  float* ctxp = (float*)p;    p += (size_t)B_SZ * HEADS * NCHK * 1024 * 4;
  float* mpart = (float*)p;   p += (size_t)B_SZ * HEADS * NCHK * 32 * 4;
  float* spart = (float*)p;   p += (size_t)B_SZ * HEADS * NCHK * 32 * 4;
  unsigned short* weff = (unsigned short*)p; p += (size_t)B_SZ * C_IN * INNER * 2;
  float* gn_part = (float*)p; p += (size_t)1024 * 2 * 4;

  cvt_w<<<dim3(384), 256, 0, stream>>>(w_qkv, w_out, wq_bf, wo_bf);
  qkv_gemm<<<dim3(64, B_SZ), 512, 0, stream>>>(wq_bf, x, qsm_t, ctxp, mpart, spart);
  ctx_weff<<<dim3(64), 256, 0, stream>>>(ctxp, mpart, spart, wo_bf, weff);
  out_gemm_t<false><<<dim3(1024), 256, 0, stream>>>(
      weff, qsm_t, nullptr, b_out, gn_part, nullptr, nullptr);
  out_gemm_t<true><<<dim3(1024), 256, 0, stream>>>(
      weff, qsm_t, out, b_out, gn_part, gamma, beta);
}